// Round 4
// baseline (437.761 us; speedup 1.0000x reference)
//
#include <hip/hip_runtime.h>
#include <hip/hip_cooperative_groups.h>

namespace cg = cooperative_groups;

#define IN_DIM 128
#define OUT_DIM 128
#define NUM_RELS 8
#define SCAN_ELEMS 2048   // fallback path: per block, 256 thr x 8

typedef unsigned short u16;
typedef u16 u16x8 __attribute__((ext_vector_type(8)));
typedef u16 u16x4 __attribute__((ext_vector_type(4)));
typedef __bf16 bf16x8 __attribute__((ext_vector_type(8)));
typedef float f32x4 __attribute__((ext_vector_type(4)));

__device__ __forceinline__ u16 f2bf(float f) {
    unsigned u = __float_as_uint(f);
    u += 0x7FFF + ((u >> 16) & 1);      // RNE
    return (u16)(u >> 16);
}
__device__ __forceinline__ float bf2f(u16 h) {
    return __uint_as_float((unsigned)h << 16);
}

#define NPB 32
#define LDK 392

// gather one K-chunk's rels [r0,r1) for one node into a 16-lane-group LDS row.
// edges in packed[beg..end) arrive sorted by rel; accumulate fp32, flush bf16.
__device__ __forceinline__ void gather_into(
    u16* arow, const u16* __restrict__ xb, const int* __restrict__ packed,
    int beg, int end, int r0, int r1, int lo)
{
    float a0=0.f,a1=0.f,a2=0.f,a3=0.f,a4=0.f,a5=0.f,a6=0.f,a7=0.f;
    int cur = r0;

#define FLUSH_() { u16x8 o_; \
    o_[0]=f2bf(a0); o_[1]=f2bf(a1); o_[2]=f2bf(a2); o_[3]=f2bf(a3); \
    o_[4]=f2bf(a4); o_[5]=f2bf(a5); o_[6]=f2bf(a6); o_[7]=f2bf(a7); \
    *(u16x8*)(arow + ((cur - r0) << 7) + lo) = o_; \
    a0=0.f;a1=0.f;a2=0.f;a3=0.f;a4=0.f;a5=0.f;a6=0.f;a7=0.f; }

#define PROC_(p_, v_) { const int r_ = (p_) >> 17; \
    while (cur < r_) { FLUSH_(); ++cur; } \
    a0 += bf2f((v_)[0]); a1 += bf2f((v_)[1]); a2 += bf2f((v_)[2]); a3 += bf2f((v_)[3]); \
    a4 += bf2f((v_)[4]); a5 += bf2f((v_)[5]); a6 += bf2f((v_)[6]); a7 += bf2f((v_)[7]); }

    int k = beg;
    for (; k + 4 <= end; k += 4) {
        const int p0 = packed[k],     p1 = packed[k + 1];
        const int p2 = packed[k + 2], p3 = packed[k + 3];
        const u16x8 v0 = *(const u16x8*)(xb + ((size_t)(p0 & 0x1FFFF) << 7) + lo);
        const u16x8 v1 = *(const u16x8*)(xb + ((size_t)(p1 & 0x1FFFF) << 7) + lo);
        const u16x8 v2 = *(const u16x8*)(xb + ((size_t)(p2 & 0x1FFFF) << 7) + lo);
        const u16x8 v3 = *(const u16x8*)(xb + ((size_t)(p3 & 0x1FFFF) << 7) + lo);
        PROC_(p0, v0); PROC_(p1, v1); PROC_(p2, v2); PROC_(p3, v3);
    }
    for (; k < end; ++k) {
        const int p = packed[k];
        const u16x8 v = *(const u16x8*)(xb + ((size_t)(p & 0x1FFFF) << 7) + lo);
        PROC_(p, v);
    }
    while (cur < r1) { FLUSH_(); ++cur; }   // empty rels -> explicit zeros
#undef PROC_
#undef FLUSH_
}

// ---------- R4: single cooperative mega-kernel ----------
// S0 prep (cast x->bf16, build WbT[col][k], zero cursor) | gsync
// S1 (dst,rel) histogram                                 | gsync
// S2a block-local scans (4096/blk) -> bsum               | gsync
// S2b every block rescans bsum (<=256) in LDS, applies   | gsync
// S3 fill packed[(rel<<17)|src] grouped by (dst,rel)     | gsync
// S4 fused gather->MFMA->bias->relu, grid-stride tiles, DOUBLE-BUFFERED agg:
//    gather(ck+1)->buf[(ck+1)&1] issued BEFORE mfma(ck) on buf[ck&1], one
//    barrier per chunk (R3 had two) -> fast waves enter MFMA while slow
//    gatherers' loads are in flight.
// LDS = 2*32*392*2 + 512*4 = 52224 B -> 3 blocks/CU, launch_bounds(512,6).
// Replaces 6 serialized dispatches (memset+prep+scan1+scan23+fill+fused):
// R1-R3 showed a constant ~137us of non-fused time vs ~35-40us of real work.
__global__ __launch_bounds__(512, 6) void mega_rgcn(
    const float* __restrict__ x, const float* __restrict__ weight,
    const float* __restrict__ slw, const float* __restrict__ bias,
    const int* __restrict__ src, const int* __restrict__ dst,
    const int* __restrict__ et,
    u16* __restrict__ xb, u16* __restrict__ WbT,
    int* __restrict__ row_ptr, int* __restrict__ cursor,
    int* __restrict__ packed, int* __restrict__ bsum,
    float* __restrict__ out,
    int N, int E, int n8, int ntiles)
{
    __shared__ u16 agg[2][NPB][LDK];   // 50176 B
    __shared__ int s[512];             //  2048 B

    cg::grid_group grid = cg::this_grid();

    const int tid = threadIdx.x;
    const int gtid = blockIdx.x * 512 + tid;
    const int gstride = gridDim.x * 512;

    // ---- S0: cast x -> xb, build WbT, zero cursor ----
    {
        const int xq = N * 32;             // N*128/4 float4 quads
        const int wq = 128 * 1152 / 4;     // 36864
        const int cq = n8 >> 2;
        const int tot = xq + wq + cq;
        for (int i = gtid; i < tot; i += gstride) {
            if (i < xq) {
                const int e = i << 2;
                const float4 v = *(const float4*)(x + e);
                u16x4 o;
                o[0]=f2bf(v.x); o[1]=f2bf(v.y); o[2]=f2bf(v.z); o[3]=f2bf(v.w);
                *(u16x4*)(xb + e) = o;
            } else if (i < xq + wq) {
                const int ii = (i - xq) << 2;   // elem idx into WbT[128][1152]
                const int col = ii / 1152;
                const int kk  = ii - col * 1152;
                u16x4 o;
                #pragma unroll
                for (int j = 0; j < 4; ++j) {
                    const int kj = kk + j;
                    const float f = (kj < 1024)
                        ? weight[((kj >> 7) << 14) + ((kj & 127) << 7) + col]
                        : slw[((kj - 1024) << 7) + col];
                    o[j] = f2bf(f);
                }
                *(u16x4*)(WbT + ii) = o;
            } else {
                const int ii = (i - xq - wq) << 2;
                *(int4*)(cursor + ii) = make_int4(0, 0, 0, 0);
            }
        }
        if (gtid == 0) row_ptr[n8] = E;
    }
    grid.sync();

    // ---- S1: (dst,rel) histogram ----
    for (int e = gtid; e < E; e += gstride)
        atomicAdd(&cursor[(dst[e] << 3) + et[e]], 1);
    grid.sync();

    // ---- S2a: block-local exclusive scans, 4096 elems/block ----
    const int nchunks = (n8 + 4095) >> 12;   // <=256 for N<=131072
    for (int c = blockIdx.x; c < nchunks; c += gridDim.x) {
        const int base = (c << 12) + (tid << 3);
        int v[8]; int sum = 0;
        #pragma unroll
        for (int j = 0; j < 8; ++j) {
            const int i = base + j;
            v[j] = (i < n8) ? cursor[i] : 0;
            sum += v[j];
        }
        s[tid] = sum;
        __syncthreads();
        #pragma unroll
        for (int off = 1; off < 512; off <<= 1) {
            const int y = (tid >= off) ? s[tid - off] : 0;
            __syncthreads();
            s[tid] += y;
            __syncthreads();
        }
        int run = s[tid] - sum;
        #pragma unroll
        for (int j = 0; j < 8; ++j) {
            const int i = base + j;
            if (i < n8) row_ptr[i] = run;
            run += v[j];
        }
        if (tid == 511) bsum[c] = s[511];
        __syncthreads();
    }
    grid.sync();

    // ---- S2b: rescan bsum in LDS, apply chunk offsets, init fill-cursor ----
    for (int c = blockIdx.x; c < nchunks; c += gridDim.x) {
        if (tid < 256) s[tid] = (tid < nchunks) ? bsum[tid] : 0;
        __syncthreads();
        #pragma unroll
        for (int off = 1; off < 256; off <<= 1) {
            int y = 0;
            if (tid < 256 && tid >= off) y = s[tid - off];
            __syncthreads();
            if (tid < 256) s[tid] += y;
            __syncthreads();
        }
        const int myoff = (c == 0) ? 0 : s[c - 1];
        const int base = (c << 12) + (tid << 3);
        #pragma unroll
        for (int j = 0; j < 8; ++j) {
            const int i = base + j;
            if (i < n8) {
                const int val = row_ptr[i] + myoff;
                row_ptr[i] = val;
                cursor[i] = val;
            }
        }
        __syncthreads();
    }
    grid.sync();

    // ---- S3: fill packed, grouped by (dst,rel) ----
    for (int e = gtid; e < E; e += gstride) {
        const int pos = atomicAdd(&cursor[(dst[e] << 3) + et[e]], 1);
        packed[pos] = (et[e] << 17) | src[e];
    }
    grid.sync();

    // ---- S4: fused gather -> GEMM -> bias -> relu ----
    const int lane = tid & 63;
    const int wv = tid >> 6;           // 0..7
    const int q = lane >> 4, l = lane & 15;
    const int cbase = wv << 4;         // wave's 16-col slab
    const int grp = tid >> 4;          // 0..31 gather groups, 1 node each
    const int lo  = (tid & 15) * 8;
    const float bv = bias[cbase + l];

    for (int tile = blockIdx.x; tile < ntiles; tile += gridDim.x) {
        const int n0 = tile * NPB;
        const int gn = n0 + grp;
        int rp0 = 0, rp3 = 0, rp6 = 0, rp8 = 0;
        if (gn < N) {
            const int rb = gn << 3;
            rp0 = row_ptr[rb];     rp3 = row_ptr[rb + 3];
            rp6 = row_ptr[rb + 6]; rp8 = row_ptr[rb + 8];
        }
        f32x4 acc[2] = {};

        // prologue: chunk 0 (rels 0..2) -> buf0
        if (gn < N) gather_into(&agg[0][grp][0], xb, packed, rp0, rp3, 0, 3, lo);
        __syncthreads();

        #pragma unroll
        for (int ck = 0; ck < 3; ++ck) {
            // issue next chunk's gather into the other buffer FIRST (no barrier
            // between gather-issue and mfma: loads fly under the MFMA sweep)
            if (ck == 0 && gn < N)
                gather_into(&agg[1][grp][0], xb, packed, rp3, rp6, 3, 6, lo);
            if (ck == 1 && gn < N) {
                gather_into(&agg[0][grp][0], xb, packed, rp6, rp8, 6, 8, lo);
                const u16x8 sv = *(const u16x8*)(xb + ((size_t)gn << 7) + lo);
                *(u16x8*)(&agg[0][grp][0] + 256 + lo) = sv;   // self-loop row
            }
            // mfma: acc += agg_chunk(buf[ck&1]) @ W_chunk
            const u16* Bp = WbT + (size_t)(cbase + l) * 1152 + ck * 384 + (q << 3);
            u16 (*ab)[LDK] = agg[ck & 1];
            #pragma unroll
            for (int kk = 0; kk < 12; ++kk) {
                const int k0 = (kk << 5) + (q << 3);
                const bf16x8 b  = __builtin_bit_cast(bf16x8, *(const u16x8*)(Bp + (kk << 5)));
                const bf16x8 a0 = __builtin_bit_cast(bf16x8, *(const u16x8*)(&ab[l][k0]));
                const bf16x8 a1 = __builtin_bit_cast(bf16x8, *(const u16x8*)(&ab[16 + l][k0]));
                acc[0] = __builtin_amdgcn_mfma_f32_16x16x32_bf16(a0, b, acc[0], 0, 0, 0);
                acc[1] = __builtin_amdgcn_mfma_f32_16x16x32_bf16(a1, b, acc[1], 0, 0, 0);
            }
            __syncthreads();   // chunk ck consumed by ALL waves; buf[ck&1] free
        }

        // epilogue: C layout col=lane&15, row=(lane>>4)*4+j; +bias, relu
        #pragma unroll
        for (int m = 0; m < 2; ++m) {
            const int rbase = n0 + (m << 4) + (q << 2);
            #pragma unroll
            for (int j = 0; j < 4; ++j) {
                const int row = rbase + j;
                if (row < N)
                    out[(size_t)row * 128 + cbase + l] = fmaxf(acc[m][j] + bv, 0.f);
            }
        }
    }
}

// ================= fallback path (R3, known-good) =================
__global__ __launch_bounds__(256) void k_prep(
    const float* __restrict__ x, const float* __restrict__ weight,
    const float* __restrict__ slw,
    const int* __restrict__ dst, const int* __restrict__ et,
    u16* __restrict__ xb, u16* __restrict__ WbT, int* __restrict__ cursor,
    int N, int E, int BA, int BB)
{
    const int b = blockIdx.x;
    const int tid = threadIdx.x;
    if (b < BA) {
        long i = ((long)b * 256 + tid) * 4;
        if (i < (long)N * 128) {
            float4 v = *(const float4*)(x + i);
            u16x4 o;
            o[0] = f2bf(v.x); o[1] = f2bf(v.y); o[2] = f2bf(v.z); o[3] = f2bf(v.w);
            *(u16x4*)(xb + i) = o;
        }
    } else if (b < BA + BB) {
        int i = ((b - BA) * 256 + tid) * 4;
        if (i < 128 * 1152) {
            const int col = i / 1152;
            const int kk  = i - col * 1152;
            u16x4 o;
            #pragma unroll
            for (int j = 0; j < 4; ++j) {
                const int kj = kk + j;
                const float f = (kj < 1024)
                    ? weight[((kj >> 7) << 14) + ((kj & 127) << 7) + col]
                    : slw[((kj - 1024) << 7) + col];
                o[j] = f2bf(f);
            }
            *(u16x4*)(WbT + i) = o;
        }
    } else {
        int e = (b - BA - BB) * 256 + tid;
        if (e < E) atomicAdd(&cursor[(dst[e] << 3) + et[e]], 1);
    }
}

__global__ __launch_bounds__(256) void k_scan1(
    const int* __restrict__ deg, int* __restrict__ local,
    int* __restrict__ bsum, int n)
{
    __shared__ int s[256];
    const int t = threadIdx.x;
    const int base = blockIdx.x * SCAN_ELEMS + t * 8;
    int v[8];
    int sum = 0;
    #pragma unroll
    for (int j = 0; j < 8; ++j) {
        int i = base + j;
        v[j] = (i < n) ? deg[i] : 0;
        sum += v[j];
    }
    s[t] = sum;
    __syncthreads();
    #pragma unroll
    for (int off = 1; off < 256; off <<= 1) {
        int y = (t >= off) ? s[t - off] : 0;
        __syncthreads();
        s[t] += y;
        __syncthreads();
    }
    int run = s[t] - sum;
    #pragma unroll
    for (int j = 0; j < 8; ++j) {
        int i = base + j;
        if (i < n) local[i] = run;
        run += v[j];
    }
    if (t == 255) bsum[blockIdx.x] = s[255];
}

__global__ __launch_bounds__(256) void k_scan23(
    int* __restrict__ row_ptr, const int* __restrict__ bsum,
    int* __restrict__ cursor, int B, int n)
{
    __shared__ int s[256];
    const int t = threadIdx.x;
    int v = (t < B) ? bsum[t] : 0;
    s[t] = v;
    __syncthreads();
    #pragma unroll
    for (int off = 1; off < 256; off <<= 1) {
        int y = (t >= off) ? s[t - off] : 0;
        __syncthreads();
        s[t] += y;
        __syncthreads();
    }
    const int myoff = (blockIdx.x == 0) ? 0 : s[blockIdx.x - 1];
    const int total = s[255];
    const int base = blockIdx.x * SCAN_ELEMS + t * 8;
    #pragma unroll
    for (int j = 0; j < 8; ++j) {
        int i = base + j;
        if (i < n) {
            int val = row_ptr[i] + myoff;
            row_ptr[i] = val;
            cursor[i] = val;
        }
    }
    if (blockIdx.x == 0 && t == 0) row_ptr[n] = total;
}

__global__ __launch_bounds__(256) void k_fill(
    const int* __restrict__ src, const int* __restrict__ dst,
    const int* __restrict__ et, int* __restrict__ cursor,
    int* __restrict__ packed, int E)
{
    int e = blockIdx.x * blockDim.x + threadIdx.x;
    if (e >= E) return;
    int pos = atomicAdd(&cursor[(dst[e] << 3) + et[e]], 1);
    packed[pos] = (et[e] << 17) | src[e];
}

__global__ __launch_bounds__(512, 8) void fused_rgcn(
    const u16* __restrict__ xb, const u16* __restrict__ WbT,
    const float* __restrict__ bias,
    const int* __restrict__ row_ptr, const int* __restrict__ packed,
    float* __restrict__ out, int N)
{
    __shared__ u16 agg[NPB][LDK];

    const int tid = threadIdx.x;
    const int n0 = blockIdx.x * NPB;
    const int lane = tid & 63;
    const int wv = tid >> 6;
    const int q = lane >> 4, l = lane & 15;
    const int cbase = wv << 4;
    const int grp = tid >> 4;
    const int lo  = (tid & 15) * 8;

    const int gn = n0 + grp;
    u16* arow = &agg[grp][0];

    f32x4 acc[2] = {};

    for (int ck = 0; ck < 3; ++ck) {
        const int r0 = ck * 3;
        const int r1 = (ck == 2) ? 8 : r0 + 3;
        if (gn < N) {
            const int beg = row_ptr[(gn << 3) + r0];
            const int end = row_ptr[(gn << 3) + r1];
            gather_into(arow, xb, packed, beg, end, r0, r1, lo);
            if (ck == 2) {
                const u16x8 sv = *(const u16x8*)(xb + ((size_t)gn << 7) + lo);
                *(u16x8*)(arow + 256 + lo) = sv;
            }
        }
        __syncthreads();

        const u16* Bp = WbT + (size_t)(cbase + l) * 1152 + ck * 384 + (q << 3);
        #pragma unroll
        for (int kk = 0; kk < 12; ++kk) {
            const int k0 = (kk << 5) + (q << 3);
            const bf16x8 b  = __builtin_bit_cast(bf16x8, *(const u16x8*)(Bp + (kk << 5)));
            const bf16x8 a0 = __builtin_bit_cast(bf16x8, *(const u16x8*)(&agg[l][k0]));
            const bf16x8 a1 = __builtin_bit_cast(bf16x8, *(const u16x8*)(&agg[16 + l][k0]));
            acc[0] = __builtin_amdgcn_mfma_f32_16x16x32_bf16(a0, b, acc[0], 0, 0, 0);
            acc[1] = __builtin_amdgcn_mfma_f32_16x16x32_bf16(a1, b, acc[1], 0, 0, 0);
        }
        if (ck < 2) __syncthreads();
    }

    const float bv = bias[cbase + l];
    #pragma unroll
    for (int m = 0; m < 2; ++m) {
        const int rbase = n0 + (m << 4) + (q << 2);
        #pragma unroll
        for (int j = 0; j < 4; ++j) {
            const int row = rbase + j;
            if (row < N)
                out[(size_t)row * 128 + cbase + l] = fmaxf(acc[m][j] + bv, 0.f);
        }
    }
}

// ---------- fp32 fallback kernels ----------
__global__ __launch_bounds__(256) void gemm128(
    const float* __restrict__ x, const float* __restrict__ W,
    const float* __restrict__ bias, float* __restrict__ out, int N)
{
    __shared__ float Ws[IN_DIM * OUT_DIM];
    __shared__ float xs[16][IN_DIM];

    const float* Wz = W + (size_t)blockIdx.z * IN_DIM * OUT_DIM;
    float* outz = out + (size_t)blockIdx.z * (size_t)N * OUT_DIM;

    {
        const float4* s4 = (const float4*)Wz;
        float4* d4 = (float4*)Ws;
        for (int i = threadIdx.x; i < IN_DIM * OUT_DIM / 4; i += 256)
            d4[i] = s4[i];
    }

    const int tid = threadIdx.x;
    const int nl = (tid >> 5) * 2;
    const int og = (tid & 31) * 4;

    float4 b4 = make_float4(0.f, 0.f, 0.f, 0.f);
    if (bias) b4 = *(const float4*)&bias[og];

    const int nchunks = (N + 15) / 16;
    for (int chunk = blockIdx.x; chunk < nchunks; chunk += gridDim.x) {
        const int n0 = chunk * 16;
        const int rows = min(16, N - n0);
        __syncthreads();
        {
            const float4* xsrc = (const float4*)(x + (size_t)n0 * IN_DIM);
            float4* xdst = (float4*)&xs[0][0];
            const int n4 = rows * (IN_DIM / 4);
            for (int i = tid; i < n4; i += 256) xdst[i] = xsrc[i];
        }
        __syncthreads();

        if (nl < rows) {
            float a00 = 0.f, a01 = 0.f, a02 = 0.f, a03 = 0.f;
            float a10 = 0.f, a11 = 0.f, a12 = 0.f, a13 = 0.f;
            #pragma unroll 8
            for (int d = 0; d < IN_DIM; ++d) {
                const float4 w4 = *(const float4*)&Ws[d * OUT_DIM + og];
                const float xa = xs[nl][d];
                const float xb = xs[nl + 1][d];
                a00 += xa * w4.x; a01 += xa * w4.y; a02 += xa * w4.z; a03 += xa * w4.w;
                a10 += xb * w4.x; a11 += xb * w4.y; a12 += xb * w4.z; a13 += xb * w4.w;
            }
            float4 r0 = make_float4(a00 + b4.x, a01 + b4.y, a02 + b4.z, a03 + b4.w);
            *(float4*)&outz[(size_t)(n0 + nl) * OUT_DIM + og] = r0;
            if (nl + 1 < rows) {
                float4 r1 = make_float4(a10 + b4.x, a11 + b4.y, a12 + b4.z, a13 + b4.w);
                *(float4*)&outz[(size_t)(n0 + nl + 1) * OUT_DIM + og] = r1;
            }
        }
    }
}

__global__ __launch_bounds__(256) void edge_direct(
    const float* __restrict__ x, const float* __restrict__ W,
    const int* __restrict__ src, const int* __restrict__ dst,
    const int* __restrict__ et, float* __restrict__ out, int E)
{
    long t = (long)blockIdx.x * blockDim.x + threadIdx.x;
    long e = t >> 6;
    int lane = (int)(t & 63);
    if (e >= E) return;
    int s = src[e], d = dst[e], r = et[e];
    const float* xr = x + (long)s * IN_DIM;
    float2 xv = *(const float2*)(xr + lane * 2);
    const float* Wr = W + (long)r * IN_DIM * OUT_DIM;
    const int o0 = lane * 2;
    float a0 = 0.f, a1 = 0.f;
    #pragma unroll 8
    for (int dd = 0; dd < 64; ++dd) {
        float xa = __shfl(xv.x, dd);
        float xb = __shfl(xv.y, dd);
        a0 += xa * Wr[(2 * dd) * OUT_DIM + o0]     + xb * Wr[(2 * dd + 1) * OUT_DIM + o0];
        a1 += xa * Wr[(2 * dd) * OUT_DIM + o0 + 1] + xb * Wr[(2 * dd + 1) * OUT_DIM + o0 + 1];
    }
    atomicAdd(out + (long)d * OUT_DIM + o0, a0);
    atomicAdd(out + (long)d * OUT_DIM + o0 + 1, a1);
}

__global__ __launch_bounds__(256) void relu_k(float* __restrict__ out, long n4)
{
    long i = (long)blockIdx.x * blockDim.x + threadIdx.x;
    if (i >= n4) return;
    float4 v = ((float4*)out)[i];
    v.x = fmaxf(v.x, 0.f); v.y = fmaxf(v.y, 0.f);
    v.z = fmaxf(v.z, 0.f); v.w = fmaxf(v.w, 0.f);
    ((float4*)out)[i] = v;
}

static inline size_t align256(size_t x) { return (x + 255) & ~(size_t)255; }

extern "C" void kernel_launch(void* const* d_in, const int* in_sizes, int n_in,
                              void* d_out, int out_size, void* d_ws, size_t ws_size,
                              hipStream_t stream)
{
    const float* x      = (const float*)d_in[0];
    const float* weight = (const float*)d_in[1];
    const float* slw    = (const float*)d_in[2];
    const float* bias   = (const float*)d_in[3];
    const int*   ei     = (const int*)d_in[4];
    const int*   et     = (const int*)d_in[5];

    const int N = in_sizes[0] / IN_DIM;
    const int E = in_sizes[5];
    const int* src  = ei;
    const int* dstp = ei + E;

    float* out = (float*)d_out;

    const int n8 = N * 8;   // CSR bins keyed (dst<<3)|rel

    // workspace layout (bf16 fused path)
    size_t off = 0;
    const size_t xb_off   = off; off += align256((size_t)N * 128 * 2);
    const size_t wb_off   = off; off += align256((size_t)128 * 1152 * 2);
    const size_t rp_off   = off; off += align256((size_t)(n8 + 1) * 4);
    const size_t cur_off  = off; off += align256((size_t)n8 * 4);
    const size_t pk_off   = off; off += align256((size_t)E * 4);
    const size_t bs_off   = off; off += align256(256 * 4);
    const size_t need_bf16 = off;

    const int scanB = (n8 + SCAN_ELEMS - 1) / SCAN_ELEMS;

    if (ws_size >= need_bf16 && N <= (1 << 17) && scanB <= 256) {
        char* base   = (char*)d_ws;
        u16* xb      = (u16*)(base + xb_off);
        u16* WbT     = (u16*)(base + wb_off);
        int* row_ptr = (int*)(base + rp_off);
        int* cursor  = (int*)(base + cur_off);
        int* packed  = (int*)(base + pk_off);
        int* bsum    = (int*)(base + bs_off);

        const int ntiles = (N + NPB - 1) / NPB;

        // one-time: co-resident grid capacity for cooperative launch
        static int s_G = -2;          // -2 uncomputed, -1 cooperative unusable
        if (s_G == -2) {
            int dev = 0;
            (void)hipGetDevice(&dev);
            int ncu = 0;
            if (hipDeviceGetAttribute(&ncu, hipDeviceAttributeMultiprocessorCount,
                                      dev) != hipSuccess || ncu <= 0)
                ncu = 256;
            int maxb = 0;
            if (hipOccupancyMaxActiveBlocksPerMultiprocessor(
                    &maxb, reinterpret_cast<const void*>(&mega_rgcn), 512, 0)
                    != hipSuccess)
                maxb = 0;
            s_G = (maxb >= 1) ? ((ncu * maxb > 2048) ? 2048 : ncu * maxb) : -1;
        }

        bool launched = false;
        if (s_G > 0) {
            int Nv = N, Ev = E, n8v = n8, ntv = ntiles;
            void* args[] = {
                (void*)&x, (void*)&weight, (void*)&slw, (void*)&bias,
                (void*)&src, (void*)&dstp, (void*)&et,
                (void*)&xb, (void*)&WbT, (void*)&row_ptr, (void*)&cursor,
                (void*)&packed, (void*)&bsum, (void*)&out,
                (void*)&Nv, (void*)&Ev, (void*)&n8v, (void*)&ntv
            };
            hipError_t err = hipLaunchCooperativeKernel(
                reinterpret_cast<const void*>(&mega_rgcn),
                dim3(s_G), dim3(512), args, 0, stream);
            if (err == hipSuccess) launched = true;
            else s_G = -1;   // don't retry cooperative in later iterations
        }

        if (!launched) {
            // R3 known-good multi-kernel path
            hipMemsetAsync(cursor, 0, (size_t)n8 * sizeof(int), stream);
            const int BA = (int)(((long)N * 128 / 4 + 255) / 256);
            const int BB = (128 * 1152 / 4 + 255) / 256;
            const int BD = (E + 255) / 256;
            k_prep<<<dim3(BA + BB + BD), 256, 0, stream>>>(
                x, weight, slw, dstp, et, xb, WbT, cursor, N, E, BA, BB);
            k_scan1<<<dim3(scanB), 256, 0, stream>>>(cursor, row_ptr, bsum, n8);
            k_scan23<<<dim3(scanB), 256, 0, stream>>>(row_ptr, bsum, cursor, scanB, n8);
            k_fill<<<dim3((E + 255) / 256), 256, 0, stream>>>(src, dstp, et, cursor, packed, E);
            fused_rgcn<<<dim3((N + NPB - 1) / NPB), 512, 0, stream>>>(
                xb, WbT, bias, row_ptr, packed, out, N);
        }
    } else if (ws_size >= (size_t)NUM_RELS * N * 128 * 4) {
        gemm128<<<dim3(512, 1, 1), 256, 0, stream>>>(x, slw, bias, out, N);
        long nt = (long)E * 64;
        edge_direct<<<dim3((nt + 255) / 256), 256, 0, stream>>>(x, weight, src, dstp, et, out, E);
        long n4 = (long)N * OUT_DIM / 4;
        relu_k<<<dim3((n4 + 255) / 256), 256, 0, stream>>>(out, n4);
    } else {
        gemm128<<<dim3(512, 1, 1), 256, 0, stream>>>(x, slw, bias, out, N);
        long nt = (long)E * 64;
        edge_direct<<<dim3((nt + 255) / 256), 256, 0, stream>>>(x, weight, src, dstp, et, out, E);
        long n4 = (long)N * OUT_DIM / 4;
        relu_k<<<dim3((n4 + 255) / 256), 256, 0, stream>>>(out, n4);
    }
}

// Round 5
// 319.989 us; speedup vs baseline: 1.3680x; 1.3680x over previous
//
#include <hip/hip_runtime.h>

#define IN_DIM 128
#define OUT_DIM 128
#define NUM_RELS 8

typedef unsigned short u16;
typedef u16 u16x8 __attribute__((ext_vector_type(8)));
typedef u16 u16x4 __attribute__((ext_vector_type(4)));
typedef __bf16 bf16x8 __attribute__((ext_vector_type(8)));
typedef float f32x4 __attribute__((ext_vector_type(4)));

__device__ __forceinline__ u16 f2bf(float f) {
    unsigned u = __float_as_uint(f);
    u += 0x7FFF + ((u >> 16) & 1);      // RNE
    return (u16)(u >> 16);
}
__device__ __forceinline__ float bf2f(u16 h) {
    return __uint_as_float((unsigned)h << 16);
}

// ---------- prep: cast x -> bf16, build WbT [col][k] (k = rel*128+kin,
// k 1024..1151 = self-loop), (dst,rel) histogram (cursor pre-zeroed) ----------
__global__ __launch_bounds__(256) void k_prep(
    const float* __restrict__ x, const float* __restrict__ weight,
    const float* __restrict__ slw,
    const int* __restrict__ dst, const int* __restrict__ et,
    u16* __restrict__ xb, u16* __restrict__ WbT, int* __restrict__ cursor,
    int* __restrict__ row_ptr,
    int N, int E, int n8, int BA, int BB)
{
    const int b = blockIdx.x;
    const int tid = threadIdx.x;
    if (b == 0 && tid == 0) row_ptr[n8] = E;
    if (b < BA) {
        long i = ((long)b * 256 + tid) * 4;
        if (i < (long)N * 128) {
            float4 v = *(const float4*)(x + i);
            u16x4 o;
            o[0] = f2bf(v.x); o[1] = f2bf(v.y); o[2] = f2bf(v.z); o[3] = f2bf(v.w);
            *(u16x4*)(xb + i) = o;
        }
    } else if (b < BA + BB) {
        int i = ((b - BA) * 256 + tid) * 4;      // elem idx into WbT[128][1152]
        if (i < 128 * 1152) {
            const int col = i / 1152;
            const int kk  = i - col * 1152;
            u16x4 o;
            #pragma unroll
            for (int j = 0; j < 4; ++j) {
                const int kj = kk + j;
                const float f = (kj < 1024)
                    ? weight[((kj >> 7) << 14) + ((kj & 127) << 7) + col]
                    : slw[((kj - 1024) << 7) + col];
                o[j] = f2bf(f);
            }
            *(u16x4*)(WbT + i) = o;
        }
    } else {
        int e = (b - BA - BB) * 256 + tid;
        if (e < E) atomicAdd(&cursor[(dst[e] << 3) + et[e]], 1);
    }
}

// ---------- single-kernel scan: decoupled lookback over 4096-elem chunks ----
// grid = nchunks (<=256), 512 thr, all blocks trivially co-resident (2KB LDS)
// so the spin cannot deadlock. part[c] packs {status:32|value:32}, status
// 0=invalid 1=aggregate 2=inclusive; relaxed 64-bit atomics (value rides in
// the same word, no fence needed). Writes row_ptr AND cursor (fill start).
__global__ __launch_bounds__(512) void k_scan_lb(
    const int* __restrict__ deg, int* __restrict__ row_ptr,
    int* __restrict__ cursor, unsigned long long* __restrict__ part, int n)
{
    __shared__ int s[512];
    __shared__ int s_exc;
    const int c = blockIdx.x;
    const int t = threadIdx.x;
    const int base = (c << 12) + (t << 3);
    int v[8]; int sum = 0;
    #pragma unroll
    for (int j = 0; j < 8; ++j) {
        const int i = base + j;
        v[j] = (i < n) ? deg[i] : 0;
        sum += v[j];
    }
    s[t] = sum;
    __syncthreads();
    #pragma unroll
    for (int off = 1; off < 512; off <<= 1) {
        const int y = (t >= off) ? s[t - off] : 0;
        __syncthreads();
        s[t] += y;
        __syncthreads();
    }
    const int total = s[511];
    const int run = s[t] - sum;

    if (t == 0) {
        const unsigned long long st = (c == 0) ? 2ULL : 1ULL;
        __hip_atomic_store(&part[c], (st << 32) | (unsigned int)total,
                           __ATOMIC_RELAXED, __HIP_MEMORY_SCOPE_AGENT);
    }

    int exc = 0;
    if (c > 0 && t < 64) {
        int bj = c - 1;
        while (true) {
            const int idx = bj - t;
            unsigned long long w = 0;
            if (idx >= 0) {
                do {
                    w = __hip_atomic_load(&part[idx], __ATOMIC_RELAXED,
                                          __HIP_MEMORY_SCOPE_AGENT);
                } while ((w >> 32) == 0ULL);
            }
            const unsigned long long incmask =
                __ballot(idx >= 0 && (w >> 32) == 2ULL);
            const int Ls = incmask ? (__ffsll(incmask) - 1) : 64;
            unsigned int contrib =
                (idx >= 0 && t <= Ls) ? (unsigned int)(w & 0xffffffffULL) : 0u;
            #pragma unroll
            for (int o = 32; o >= 1; o >>= 1) contrib += __shfl_xor(contrib, o);
            exc += (int)contrib;
            if (Ls < 64) break;
            bj -= 64;
        }
        if (t == 0) {
            __hip_atomic_store(&part[c],
                (2ULL << 32) | (unsigned int)(exc + total),
                __ATOMIC_RELAXED, __HIP_MEMORY_SCOPE_AGENT);
            s_exc = exc;
        }
    } else if (t == 0) {
        s_exc = 0;
    }
    __syncthreads();
    exc = s_exc;
    int acc_ = exc + run;
    #pragma unroll
    for (int j = 0; j < 8; ++j) {
        const int i = base + j;
        if (i < n) { row_ptr[i] = acc_; cursor[i] = acc_; }
        acc_ += v[j];
    }
}

__global__ __launch_bounds__(256) void k_fill(
    const int* __restrict__ src, const int* __restrict__ dst,
    const int* __restrict__ et, int* __restrict__ cursor,
    int* __restrict__ packed, int E)
{
    int e = blockIdx.x * blockDim.x + threadIdx.x;
    if (e >= E) return;
    int pos = atomicAdd(&cursor[(dst[e] << 3) + et[e]], 1);
    packed[pos] = (et[e] << 17) | src[e];
}

#define NPB 32
#define LDK 392

// gather one K-chunk's rels [r0,r1) for one node into a 16-lane-group LDS row
__device__ __forceinline__ void gather_into(
    u16* arow, const u16* __restrict__ xb, const int* __restrict__ packed,
    int beg, int end, int r0, int r1, int lo)
{
    float a0=0.f,a1=0.f,a2=0.f,a3=0.f,a4=0.f,a5=0.f,a6=0.f,a7=0.f;
    int cur = r0;

#define FLUSH_() { u16x8 o_; \
    o_[0]=f2bf(a0); o_[1]=f2bf(a1); o_[2]=f2bf(a2); o_[3]=f2bf(a3); \
    o_[4]=f2bf(a4); o_[5]=f2bf(a5); o_[6]=f2bf(a6); o_[7]=f2bf(a7); \
    *(u16x8*)(arow + ((cur - r0) << 7) + lo) = o_; \
    a0=0.f;a1=0.f;a2=0.f;a3=0.f;a4=0.f;a5=0.f;a6=0.f;a7=0.f; }

#define PROC_(p_, v_) { const int r_ = (p_) >> 17; \
    while (cur < r_) { FLUSH_(); ++cur; } \
    a0 += bf2f((v_)[0]); a1 += bf2f((v_)[1]); a2 += bf2f((v_)[2]); a3 += bf2f((v_)[3]); \
    a4 += bf2f((v_)[4]); a5 += bf2f((v_)[5]); a6 += bf2f((v_)[6]); a7 += bf2f((v_)[7]); }

    int k = beg;
    for (; k + 4 <= end; k += 4) {
        const int p0 = packed[k],     p1 = packed[k + 1];
        const int p2 = packed[k + 2], p3 = packed[k + 3];
        const u16x8 v0 = *(const u16x8*)(xb + ((size_t)(p0 & 0x1FFFF) << 7) + lo);
        const u16x8 v1 = *(const u16x8*)(xb + ((size_t)(p1 & 0x1FFFF) << 7) + lo);
        const u16x8 v2 = *(const u16x8*)(xb + ((size_t)(p2 & 0x1FFFF) << 7) + lo);
        const u16x8 v3 = *(const u16x8*)(xb + ((size_t)(p3 & 0x1FFFF) << 7) + lo);
        PROC_(p0, v0); PROC_(p1, v1); PROC_(p2, v2); PROC_(p3, v3);
    }
    for (; k < end; ++k) {
        const int p = packed[k];
        const u16x8 v = *(const u16x8*)(xb + ((size_t)(p & 0x1FFFF) << 7) + lo);
        PROC_(p, v);
    }
    while (cur < r1) { FLUSH_(); ++cur; }   // empty rels -> explicit zeros
#undef PROC_
#undef FLUSH_
}

// ---------- R5: fused gather->MFMA, SOFTWARE-PIPELINED (no cooperative) -----
// Double-buffered agg (2x32x392x2 = 50176 B -> 3 blocks/CU, launch_bounds
// (512,6) = 24 waves/CU). Per chunk: gather(NEXT chunk)->buf[pb] issued
// BEFORE mfma(current)<-buf[pb^1]; ONE barrier per chunk (R3 had two).
// ck==2 prefetches the NEXT TILE's chunk-0 (persistent grid of 768 -> each
// block runs ~2 tiles), so gather latency hides under MFMA continuously.
// Buffer parity pb toggles every chunk; mfma always reads pb^1.
// Tail nodes (gn>=N) leave garbage LDS rows: MFMA row i only feeds output
// row i, and the epilogue masks rows>=N, so garbage never contaminates.
__global__ __launch_bounds__(512, 6) void fused_rgcn(
    const u16* __restrict__ xb,      // [N][128] bf16
    const u16* __restrict__ WbT,     // [128][1152] bf16 (col-major weights)
    const float* __restrict__ bias,
    const int* __restrict__ row_ptr, // [8N+1]
    const int* __restrict__ packed,  // [E]: (rel<<17)|src, grouped by (dst,rel)
    float* __restrict__ out, int N, int ntiles)
{
    __shared__ u16 agg[2][NPB][LDK];   // 50176 B

    const int tid = threadIdx.x;
    const int lane = tid & 63;
    const int wv = tid >> 6;           // 0..7
    const int q = lane >> 4, l = lane & 15;
    const int cbase = wv << 4;         // wave's 16-col slab
    const int grp = tid >> 4;          // 0..31 gather groups, 1 node each
    const int lo  = (tid & 15) * 8;
    const float bv = bias[cbase + l];
    const int gstride = gridDim.x;

    int tile = blockIdx.x;
    int gn = tile * NPB + grp;
    int rp0 = 0, rp3 = 0, rp6 = 0, rp8 = 0;
    if (gn < N) {
        const int rb = gn << 3;
        rp0 = row_ptr[rb];     rp3 = row_ptr[rb + 3];
        rp6 = row_ptr[rb + 6]; rp8 = row_ptr[rb + 8];
    }
    // prologue: chunk0 of first tile -> buf0
    if (gn < N) gather_into(&agg[0][grp][0], xb, packed, rp0, rp3, 0, 3, lo);
    __syncthreads();
    int pb = 1;

    for (; tile < ntiles; tile += gstride) {
        const int tn = tile + gstride;
        int nrp0 = 0, nrp3 = 0, nrp6 = 0, nrp8 = 0, ngn = N;
        if (tn < ntiles) {
            ngn = tn * NPB + grp;
            if (ngn < N) {
                const int rb = ngn << 3;
                nrp0 = row_ptr[rb];     nrp3 = row_ptr[rb + 3];
                nrp6 = row_ptr[rb + 6]; nrp8 = row_ptr[rb + 8];
            }
        }
        f32x4 acc[2] = {};

        #pragma unroll
        for (int ck = 0; ck < 3; ++ck) {
            // gather the NEXT chunk into buf[pb] (contents consumed at the
            // previous chunk's mfma; a barrier already separated)
            if (ck == 0) {
                if (gn < N)
                    gather_into(&agg[pb][grp][0], xb, packed, rp3, rp6, 3, 6, lo);
            } else if (ck == 1) {
                if (gn < N) {
                    gather_into(&agg[pb][grp][0], xb, packed, rp6, rp8, 6, 8, lo);
                    const u16x8 sv = *(const u16x8*)(xb + ((size_t)gn << 7) + lo);
                    *(u16x8*)(&agg[pb][grp][0] + 256 + lo) = sv;   // self-loop
                }
            } else {   // ck==2: prefetch next tile's chunk0
                if (tn < ntiles && ngn < N)
                    gather_into(&agg[pb][grp][0], xb, packed, nrp0, nrp3, 0, 3, lo);
            }
            // mfma: acc += buf[pb^1] @ W_chunk
            const u16* Bp = WbT + (size_t)(cbase + l) * 1152 + ck * 384 + (q << 3);
            u16 (*ab)[LDK] = agg[pb ^ 1];
            #pragma unroll
            for (int kk = 0; kk < 12; ++kk) {
                const int k0 = (kk << 5) + (q << 3);
                const bf16x8 b  = __builtin_bit_cast(bf16x8, *(const u16x8*)(Bp + (kk << 5)));
                const bf16x8 a0 = __builtin_bit_cast(bf16x8, *(const u16x8*)(&ab[l][k0]));
                const bf16x8 a1 = __builtin_bit_cast(bf16x8, *(const u16x8*)(&ab[16 + l][k0]));
                acc[0] = __builtin_amdgcn_mfma_f32_16x16x32_bf16(a0, b, acc[0], 0, 0, 0);
                acc[1] = __builtin_amdgcn_mfma_f32_16x16x32_bf16(a1, b, acc[1], 0, 0, 0);
            }
            __syncthreads();
            pb ^= 1;
        }

        // epilogue: C layout col=lane&15, row=(lane>>4)*4+j; +bias, relu
        #pragma unroll
        for (int m = 0; m < 2; ++m) {
            const int rbase = tile * NPB + (m << 4) + (q << 2);
            #pragma unroll
            for (int j = 0; j < 4; ++j) {
                const int row = rbase + j;
                if (row < N)
                    out[(size_t)row * 128 + cbase + l] = fmaxf(acc[m][j] + bv, 0.f);
            }
        }
        gn = ngn; rp0 = nrp0; rp3 = nrp3; rp6 = nrp6; rp8 = nrp8;
    }
}

// ---------- fp32 fallback kernels ----------
__global__ __launch_bounds__(256) void gemm128(
    const float* __restrict__ x, const float* __restrict__ W,
    const float* __restrict__ bias, float* __restrict__ out, int N)
{
    __shared__ float Ws[IN_DIM * OUT_DIM];
    __shared__ float xs[16][IN_DIM];

    const float* Wz = W + (size_t)blockIdx.z * IN_DIM * OUT_DIM;
    float* outz = out + (size_t)blockIdx.z * (size_t)N * OUT_DIM;

    {
        const float4* s4 = (const float4*)Wz;
        float4* d4 = (float4*)Ws;
        for (int i = threadIdx.x; i < IN_DIM * OUT_DIM / 4; i += 256)
            d4[i] = s4[i];
    }

    const int tid = threadIdx.x;
    const int nl = (tid >> 5) * 2;
    const int og = (tid & 31) * 4;

    float4 b4 = make_float4(0.f, 0.f, 0.f, 0.f);
    if (bias) b4 = *(const float4*)&bias[og];

    const int nchunks = (N + 15) / 16;
    for (int chunk = blockIdx.x; chunk < nchunks; chunk += gridDim.x) {
        const int n0 = chunk * 16;
        const int rows = min(16, N - n0);
        __syncthreads();
        {
            const float4* xsrc = (const float4*)(x + (size_t)n0 * IN_DIM);
            float4* xdst = (float4*)&xs[0][0];
            const int n4 = rows * (IN_DIM / 4);
            for (int i = tid; i < n4; i += 256) xdst[i] = xsrc[i];
        }
        __syncthreads();

        if (nl < rows) {
            float a00 = 0.f, a01 = 0.f, a02 = 0.f, a03 = 0.f;
            float a10 = 0.f, a11 = 0.f, a12 = 0.f, a13 = 0.f;
            #pragma unroll 8
            for (int d = 0; d < IN_DIM; ++d) {
                const float4 w4 = *(const float4*)&Ws[d * OUT_DIM + og];
                const float xa = xs[nl][d];
                const float xb = xs[nl + 1][d];
                a00 += xa * w4.x; a01 += xa * w4.y; a02 += xa * w4.z; a03 += xa * w4.w;
                a10 += xb * w4.x; a11 += xb * w4.y; a12 += xb * w4.z; a13 += xb * w4.w;
            }
            float4 r0 = make_float4(a00 + b4.x, a01 + b4.y, a02 + b4.z, a03 + b4.w);
            *(float4*)&outz[(size_t)(n0 + nl) * OUT_DIM + og] = r0;
            if (nl + 1 < rows) {
                float4 r1 = make_float4(a10 + b4.x, a11 + b4.y, a12 + b4.z, a13 + b4.w);
                *(float4*)&outz[(size_t)(n0 + nl + 1) * OUT_DIM + og] = r1;
            }
        }
    }
}

__global__ __launch_bounds__(256) void edge_direct(
    const float* __restrict__ x, const float* __restrict__ W,
    const int* __restrict__ src, const int* __restrict__ dst,
    const int* __restrict__ et, float* __restrict__ out, int E)
{
    long t = (long)blockIdx.x * blockDim.x + threadIdx.x;
    long e = t >> 6;
    int lane = (int)(t & 63);
    if (e >= E) return;
    int s = src[e], d = dst[e], r = et[e];
    const float* xr = x + (long)s * IN_DIM;
    float2 xv = *(const float2*)(xr + lane * 2);
    const float* Wr = W + (long)r * IN_DIM * OUT_DIM;
    const int o0 = lane * 2;
    float a0 = 0.f, a1 = 0.f;
    #pragma unroll 8
    for (int dd = 0; dd < 64; ++dd) {
        float xa = __shfl(xv.x, dd);
        float xb = __shfl(xv.y, dd);
        a0 += xa * Wr[(2 * dd) * OUT_DIM + o0]     + xb * Wr[(2 * dd + 1) * OUT_DIM + o0];
        a1 += xa * Wr[(2 * dd) * OUT_DIM + o0 + 1] + xb * Wr[(2 * dd + 1) * OUT_DIM + o0 + 1];
    }
    atomicAdd(out + (long)d * OUT_DIM + o0, a0);
    atomicAdd(out + (long)d * OUT_DIM + o0 + 1, a1);
}

__global__ __launch_bounds__(256) void relu_k(float* __restrict__ out, long n4)
{
    long i = (long)blockIdx.x * blockDim.x + threadIdx.x;
    if (i >= n4) return;
    float4 v = ((float4*)out)[i];
    v.x = fmaxf(v.x, 0.f); v.y = fmaxf(v.y, 0.f);
    v.z = fmaxf(v.z, 0.f); v.w = fmaxf(v.w, 0.f);
    ((float4*)out)[i] = v;
}

static inline size_t align256(size_t x) { return (x + 255) & ~(size_t)255; }

extern "C" void kernel_launch(void* const* d_in, const int* in_sizes, int n_in,
                              void* d_out, int out_size, void* d_ws, size_t ws_size,
                              hipStream_t stream)
{
    const float* x      = (const float*)d_in[0];
    const float* weight = (const float*)d_in[1];
    const float* slw    = (const float*)d_in[2];
    const float* bias   = (const float*)d_in[3];
    const int*   ei     = (const int*)d_in[4];
    const int*   et     = (const int*)d_in[5];

    const int N = in_sizes[0] / IN_DIM;
    const int E = in_sizes[5];
    const int* src  = ei;
    const int* dstp = ei + E;

    float* out = (float*)d_out;

    const int n8 = N * 8;   // CSR bins keyed (dst<<3)|rel

    // workspace layout (cursor and part contiguous -> one memset covers both)
    size_t off = 0;
    const size_t xb_off   = off; off += align256((size_t)N * 128 * 2);
    const size_t wb_off   = off; off += align256((size_t)128 * 1152 * 2);
    const size_t rp_off   = off; off += align256((size_t)(n8 + 1) * 4);
    const size_t cur_off  = off; off += align256((size_t)n8 * 4);
    const size_t pt_off   = off; off += align256(256 * 8);
    const size_t pk_off   = off; off += align256((size_t)E * 4);
    const size_t need_bf16 = off;

    const int nchunks = (n8 + 4095) >> 12;   // 4096 elems per scan block

    if (ws_size >= need_bf16 && N <= (1 << 17) && nchunks <= 256) {
        char* base   = (char*)d_ws;
        u16* xb      = (u16*)(base + xb_off);
        u16* WbT     = (u16*)(base + wb_off);
        int* row_ptr = (int*)(base + rp_off);
        int* cursor  = (int*)(base + cur_off);
        unsigned long long* part = (unsigned long long*)(base + pt_off);
        int* packed  = (int*)(base + pk_off);

        // zero cursor + lookback state in one memset
        hipMemsetAsync(base + cur_off, 0, (pt_off - cur_off) + 256 * 8, stream);

        const int BA = (int)(((long)N * 128 / 4 + 255) / 256);
        const int BB = (128 * 1152 / 4 + 255) / 256;   // 144
        const int BD = (E + 255) / 256;
        k_prep<<<dim3(BA + BB + BD), 256, 0, stream>>>(
            x, weight, slw, dstp, et, xb, WbT, cursor, row_ptr, N, E, n8, BA, BB);

        k_scan_lb<<<dim3(nchunks), 512, 0, stream>>>(cursor, row_ptr, cursor, part, n8);
        k_fill<<<dim3((E + 255) / 256), 256, 0, stream>>>(src, dstp, et, cursor, packed, E);

        const int ntiles = (N + NPB - 1) / NPB;
        const int G = ntiles < 768 ? ntiles : 768;   // 3 blocks/CU persistent
        fused_rgcn<<<dim3(G), 512, 0, stream>>>(
            xb, WbT, bias, row_ptr, packed, out, N, ntiles);
    } else if (ws_size >= (size_t)NUM_RELS * N * 128 * 4) {
        gemm128<<<dim3(512, 1, 1), 256, 0, stream>>>(x, slw, bias, out, N);
        long nt = (long)E * 64;
        edge_direct<<<dim3((nt + 255) / 256), 256, 0, stream>>>(x, weight, src, dstp, et, out, E);
        long n4 = (long)N * OUT_DIM / 4;
        relu_k<<<dim3((n4 + 255) / 256), 256, 0, stream>>>(out, n4);
    } else {
        gemm128<<<dim3(512, 1, 1), 256, 0, stream>>>(x, slw, bias, out, N);
        long nt = (long)E * 64;
        edge_direct<<<dim3((nt + 255) / 256), 256, 0, stream>>>(x, weight, src, dstp, et, out, E);
        long n4 = (long)N * OUT_DIM / 4;
        relu_k<<<dim3((n4 + 255) / 256), 256, 0, stream>>>(out, n4);
    }
}

// Round 6
// 227.714 us; speedup vs baseline: 1.9224x; 1.4052x over previous
//
#include <hip/hip_runtime.h>

#define IN_DIM 128
#define OUT_DIM 128
#define NUM_RELS 8

typedef unsigned short u16;
typedef u16 u16x8 __attribute__((ext_vector_type(8)));
typedef u16 u16x4 __attribute__((ext_vector_type(4)));
typedef __bf16 bf16x8 __attribute__((ext_vector_type(8)));
typedef float f32x4 __attribute__((ext_vector_type(4)));

__device__ __forceinline__ u16 f2bf(float f) {
    unsigned u = __float_as_uint(f);
    u += 0x7FFF + ((u >> 16) & 1);      // RNE
    return (u16)(u >> 16);
}
__device__ __forceinline__ float bf2f(u16 h) {
    return __uint_as_float((unsigned)h << 16);
}

// ---------- zero cursor + lookback state (replaces hipMemsetAsync: the
// rocclr fillBufferAligned dispatch measured 41 us for 1.6 MB in R0) ----------
__global__ __launch_bounds__(256) void k_zero(int4* __restrict__ p, int n4)
{
    int i = blockIdx.x * 256 + threadIdx.x;
    if (i < n4) p[i] = make_int4(0, 0, 0, 0);
}

// ---------- prep: cast x -> bf16, build WbT [col][k] (k = rel*128+kin,
// k 1024..1151 = self-loop), (dst,rel) histogram (cursor pre-zeroed) ----------
__global__ __launch_bounds__(256) void k_prep(
    const float* __restrict__ x, const float* __restrict__ weight,
    const float* __restrict__ slw,
    const int* __restrict__ dst, const int* __restrict__ et,
    u16* __restrict__ xb, u16* __restrict__ WbT, int* __restrict__ cursor,
    int* __restrict__ row_ptr,
    int N, int E, int n8, int BA, int BB)
{
    const int b = blockIdx.x;
    const int tid = threadIdx.x;
    if (b == 0 && tid == 0) row_ptr[n8] = E;
    if (b < BA) {
        long i = ((long)b * 256 + tid) * 4;
        if (i < (long)N * 128) {
            float4 v = *(const float4*)(x + i);
            u16x4 o;
            o[0] = f2bf(v.x); o[1] = f2bf(v.y); o[2] = f2bf(v.z); o[3] = f2bf(v.w);
            *(u16x4*)(xb + i) = o;
        }
    } else if (b < BA + BB) {
        int i = ((b - BA) * 256 + tid) * 4;      // elem idx into WbT[128][1152]
        if (i < 128 * 1152) {
            const int col = i / 1152;
            const int kk  = i - col * 1152;
            u16x4 o;
            #pragma unroll
            for (int j = 0; j < 4; ++j) {
                const int kj = kk + j;
                const float f = (kj < 1024)
                    ? weight[((kj >> 7) << 14) + ((kj & 127) << 7) + col]
                    : slw[((kj - 1024) << 7) + col];
                o[j] = f2bf(f);
            }
            *(u16x4*)(WbT + i) = o;
        }
    } else {
        int e = (b - BA - BB) * 256 + tid;
        if (e < E) atomicAdd(&cursor[(dst[e] << 3) + et[e]], 1);
    }
}

// ---------- single-kernel scan: decoupled lookback over 4096-elem chunks ----
// grid = nchunks (<=256), 512 thr, all co-resident -> spin cannot deadlock.
// part[c] = {status:32|value:32}; relaxed 64-bit atomics. Writes row_ptr AND
// cursor (fill start). [verified passing in R5]
__global__ __launch_bounds__(512) void k_scan_lb(
    const int* __restrict__ deg, int* __restrict__ row_ptr,
    int* __restrict__ cursor, unsigned long long* __restrict__ part, int n)
{
    __shared__ int s[512];
    __shared__ int s_exc;
    const int c = blockIdx.x;
    const int t = threadIdx.x;
    const int base = (c << 12) + (t << 3);
    int v[8]; int sum = 0;
    #pragma unroll
    for (int j = 0; j < 8; ++j) {
        const int i = base + j;
        v[j] = (i < n) ? deg[i] : 0;
        sum += v[j];
    }
    s[t] = sum;
    __syncthreads();
    #pragma unroll
    for (int off = 1; off < 512; off <<= 1) {
        const int y = (t >= off) ? s[t - off] : 0;
        __syncthreads();
        s[t] += y;
        __syncthreads();
    }
    const int total = s[511];
    const int run = s[t] - sum;

    if (t == 0) {
        const unsigned long long st = (c == 0) ? 2ULL : 1ULL;
        __hip_atomic_store(&part[c], (st << 32) | (unsigned int)total,
                           __ATOMIC_RELAXED, __HIP_MEMORY_SCOPE_AGENT);
    }

    int exc = 0;
    if (c > 0 && t < 64) {
        int bj = c - 1;
        while (true) {
            const int idx = bj - t;
            unsigned long long w = 0;
            if (idx >= 0) {
                do {
                    w = __hip_atomic_load(&part[idx], __ATOMIC_RELAXED,
                                          __HIP_MEMORY_SCOPE_AGENT);
                } while ((w >> 32) == 0ULL);
            }
            const unsigned long long incmask =
                __ballot(idx >= 0 && (w >> 32) == 2ULL);
            const int Ls = incmask ? (__ffsll(incmask) - 1) : 64;
            unsigned int contrib =
                (idx >= 0 && t <= Ls) ? (unsigned int)(w & 0xffffffffULL) : 0u;
            #pragma unroll
            for (int o = 32; o >= 1; o >>= 1) contrib += __shfl_xor(contrib, o);
            exc += (int)contrib;
            if (Ls < 64) break;
            bj -= 64;
        }
        if (t == 0) {
            __hip_atomic_store(&part[c],
                (2ULL << 32) | (unsigned int)(exc + total),
                __ATOMIC_RELAXED, __HIP_MEMORY_SCOPE_AGENT);
            s_exc = exc;
        }
    } else if (t == 0) {
        s_exc = 0;
    }
    __syncthreads();
    exc = s_exc;
    int acc_ = exc + run;
    #pragma unroll
    for (int j = 0; j < 8; ++j) {
        const int i = base + j;
        if (i < n) { row_ptr[i] = acc_; cursor[i] = acc_; }
        acc_ += v[j];
    }
}

__global__ __launch_bounds__(256) void k_fill(
    const int* __restrict__ src, const int* __restrict__ dst,
    const int* __restrict__ et, int* __restrict__ cursor,
    int* __restrict__ packed, int E)
{
    int e = blockIdx.x * blockDim.x + threadIdx.x;
    if (e >= E) return;
    int pos = atomicAdd(&cursor[(dst[e] << 3) + et[e]], 1);
    packed[pos] = (et[e] << 17) | src[e];
}

#define NPB 64
#define LDK 392

// gather one K-chunk's rels [r0,r1) for ONE node with an 8-LANE group.
// Each lane covers 32 B of the 256-B row via two u16x8 loads -> a 4-edge
// batch keeps 8 independent loads in flight per chain (R3: 4).
__device__ __forceinline__ void gather8(
    u16* arow, const u16* __restrict__ xb, const int* __restrict__ packed,
    int beg, int end, int r0, int r1, int lo)   // lo = (tid&7)*16 elems
{
    float a[16];
    #pragma unroll
    for (int j = 0; j < 16; ++j) a[j] = 0.f;
    int cur = r0;

    auto flush = [&]() {
        u16x8 ol, oh;
        #pragma unroll
        for (int j = 0; j < 8; ++j) {
            ol[j] = f2bf(a[j]);     a[j] = 0.f;
            oh[j] = f2bf(a[8 + j]); a[8 + j] = 0.f;
        }
        u16* p = arow + ((cur - r0) << 7) + lo;
        *(u16x8*)p = ol;
        *(u16x8*)(p + 8) = oh;
        ++cur;
    };
    auto proc = [&](int p, const u16x8& vl, const u16x8& vh) {
        const int r_ = p >> 17;
        while (cur < r_) flush();
        #pragma unroll
        for (int j = 0; j < 8; ++j) {
            a[j]     += bf2f(vl[j]);
            a[8 + j] += bf2f(vh[j]);
        }
    };

    int k = beg;
    for (; k + 4 <= end; k += 4) {
        const int p0 = packed[k],     p1 = packed[k + 1];
        const int p2 = packed[k + 2], p3 = packed[k + 3];
        const u16* b0 = xb + ((size_t)(p0 & 0x1FFFF) << 7) + lo;
        const u16* b1 = xb + ((size_t)(p1 & 0x1FFFF) << 7) + lo;
        const u16* b2 = xb + ((size_t)(p2 & 0x1FFFF) << 7) + lo;
        const u16* b3 = xb + ((size_t)(p3 & 0x1FFFF) << 7) + lo;
        const u16x8 v0l = *(const u16x8*)b0, v0h = *(const u16x8*)(b0 + 8);
        const u16x8 v1l = *(const u16x8*)b1, v1h = *(const u16x8*)(b1 + 8);
        const u16x8 v2l = *(const u16x8*)b2, v2h = *(const u16x8*)(b2 + 8);
        const u16x8 v3l = *(const u16x8*)b3, v3h = *(const u16x8*)(b3 + 8);
        proc(p0, v0l, v0h); proc(p1, v1l, v1h);
        proc(p2, v2l, v2h); proc(p3, v3l, v3h);
    }
    for (; k < end; ++k) {
        const int p = packed[k];
        const u16* b = xb + ((size_t)(p & 0x1FFFF) << 7) + lo;
        const u16x8 vl = *(const u16x8*)b, vh = *(const u16x8*)(b + 8);
        proc(p, vl, vh);
    }
    while (cur < r1) flush();   // empty rels -> explicit zeros
}

// ---------- R6: fused gather->MFMA, R3 skeleton + 8-lane gather groups -----
// 64 nodes/block, 512 thr = 64 gather chains/block; LDS 64x392x2 = 50176 B
// -> 3 blocks/CU (launch_bounds(512,6) = 24 waves/CU). 192 chains/CU x
// 8-deep batches ~ 5x R3's in-flight loads. Simple phase alternation, 2
// barriers/chunk, ONE tile per block (R5's cross-tile pipeline spilled:
// symmetric +220 MB FETCH/WRITE — do not re-add live cross-tile state).
// MFMA: 8 waves x 16 cols, 4 row-tiles each, K=384/chunk, acc[4] persists.
__global__ __launch_bounds__(512, 6) void fused_rgcn(
    const u16* __restrict__ xb,      // [N][128] bf16
    const u16* __restrict__ WbT,     // [128][1152] bf16 (col-major weights)
    const float* __restrict__ bias,
    const int* __restrict__ row_ptr, // [8N+1]
    const int* __restrict__ packed,  // [E]: (rel<<17)|src, grouped by (dst,rel)
    float* __restrict__ out, int N)
{
    __shared__ u16 agg[NPB][LDK];    // 50176 B

    const int tid = threadIdx.x;
    const int n0 = blockIdx.x * NPB;
    const int lane = tid & 63;
    const int wv = tid >> 6;           // 0..7
    const int q = lane >> 4, l = lane & 15;
    const int cbase = wv << 4;         // wave's 16-col slab
    const int grp = tid >> 3;          // 0..63 gather groups, 1 node each
    const int lo  = (tid & 7) << 4;    // 16 elems (32 B) per lane
    const int gn = n0 + grp;
    u16* arow = &agg[grp][0];
    const float bv = bias[cbase + l];

    f32x4 acc[4] = {};

    #pragma unroll 1
    for (int ck = 0; ck < 3; ++ck) {
        const int r0 = ck * 3;
        const int r1 = (ck == 2) ? 8 : r0 + 3;

        // phase 1: gather this chunk's rels (one node per 8-lane group)
        if (gn < N) {
            const int beg = row_ptr[(gn << 3) + r0];
            const int end = row_ptr[(gn << 3) + r1];
            gather8(arow, xb, packed, beg, end, r0, r1, lo);
            if (ck == 2) {               // self-loop row (local k 256..383)
                const u16* sb = xb + ((size_t)gn << 7) + lo;
                *(u16x8*)(arow + 256 + lo)     = *(const u16x8*)sb;
                *(u16x8*)(arow + 256 + lo + 8) = *(const u16x8*)(sb + 8);
            }
        }
        __syncthreads();

        // phase 2: acc += agg_chunk @ W_chunk
        const u16* Bp = WbT + (size_t)(cbase + l) * 1152 + ck * 384 + (q << 3);
        #pragma unroll
        for (int kk = 0; kk < 12; ++kk) {
            const int k0 = (kk << 5) + (q << 3);
            const bf16x8 b = __builtin_bit_cast(bf16x8, *(const u16x8*)(Bp + (kk << 5)));
            #pragma unroll
            for (int mt = 0; mt < 4; ++mt) {
                const bf16x8 a = __builtin_bit_cast(
                    bf16x8, *(const u16x8*)(&agg[(mt << 4) + l][k0]));
                acc[mt] = __builtin_amdgcn_mfma_f32_16x16x32_bf16(a, b, acc[mt], 0, 0, 0);
            }
        }
        if (ck < 2) __syncthreads();
    }

    // epilogue: C layout col=lane&15, row=(lane>>4)*4+j; +bias, relu, fp32 out
    #pragma unroll
    for (int mt = 0; mt < 4; ++mt) {
        const int rbase = n0 + (mt << 4) + (q << 2);
        #pragma unroll
        for (int j = 0; j < 4; ++j) {
            const int row = rbase + j;
            if (row < N)
                out[(size_t)row * 128 + cbase + l] = fmaxf(acc[mt][j] + bv, 0.f);
        }
    }
}

// ---------- fp32 fallback kernels ----------
__global__ __launch_bounds__(256) void gemm128(
    const float* __restrict__ x, const float* __restrict__ W,
    const float* __restrict__ bias, float* __restrict__ out, int N)
{
    __shared__ float Ws[IN_DIM * OUT_DIM];
    __shared__ float xs[16][IN_DIM];

    const float* Wz = W + (size_t)blockIdx.z * IN_DIM * OUT_DIM;
    float* outz = out + (size_t)blockIdx.z * (size_t)N * OUT_DIM;

    {
        const float4* s4 = (const float4*)Wz;
        float4* d4 = (float4*)Ws;
        for (int i = threadIdx.x; i < IN_DIM * OUT_DIM / 4; i += 256)
            d4[i] = s4[i];
    }

    const int tid = threadIdx.x;
    const int nl = (tid >> 5) * 2;
    const int og = (tid & 31) * 4;

    float4 b4 = make_float4(0.f, 0.f, 0.f, 0.f);
    if (bias) b4 = *(const float4*)&bias[og];

    const int nchunks = (N + 15) / 16;
    for (int chunk = blockIdx.x; chunk < nchunks; chunk += gridDim.x) {
        const int n0 = chunk * 16;
        const int rows = min(16, N - n0);
        __syncthreads();
        {
            const float4* xsrc = (const float4*)(x + (size_t)n0 * IN_DIM);
            float4* xdst = (float4*)&xs[0][0];
            const int n4 = rows * (IN_DIM / 4);
            for (int i = tid; i < n4; i += 256) xdst[i] = xsrc[i];
        }
        __syncthreads();

        if (nl < rows) {
            float a00 = 0.f, a01 = 0.f, a02 = 0.f, a03 = 0.f;
            float a10 = 0.f, a11 = 0.f, a12 = 0.f, a13 = 0.f;
            #pragma unroll 8
            for (int d = 0; d < IN_DIM; ++d) {
                const float4 w4 = *(const float4*)&Ws[d * OUT_DIM + og];
                const float xa = xs[nl][d];
                const float xb = xs[nl + 1][d];
                a00 += xa * w4.x; a01 += xa * w4.y; a02 += xa * w4.z; a03 += xa * w4.w;
                a10 += xb * w4.x; a11 += xb * w4.y; a12 += xb * w4.z; a13 += xb * w4.w;
            }
            float4 r0 = make_float4(a00 + b4.x, a01 + b4.y, a02 + b4.z, a03 + b4.w);
            *(float4*)&outz[(size_t)(n0 + nl) * OUT_DIM + og] = r0;
            if (nl + 1 < rows) {
                float4 r1 = make_float4(a10 + b4.x, a11 + b4.y, a12 + b4.z, a13 + b4.w);
                *(float4*)&outz[(size_t)(n0 + nl + 1) * OUT_DIM + og] = r1;
            }
        }
    }
}

__global__ __launch_bounds__(256) void edge_direct(
    const float* __restrict__ x, const float* __restrict__ W,
    const int* __restrict__ src, const int* __restrict__ dst,
    const int* __restrict__ et, float* __restrict__ out, int E)
{
    long t = (long)blockIdx.x * blockDim.x + threadIdx.x;
    long e = t >> 6;
    int lane = (int)(t & 63);
    if (e >= E) return;
    int s = src[e], d = dst[e], r = et[e];
    const float* xr = x + (long)s * IN_DIM;
    float2 xv = *(const float2*)(xr + lane * 2);
    const float* Wr = W + (long)r * IN_DIM * OUT_DIM;
    const int o0 = lane * 2;
    float a0 = 0.f, a1 = 0.f;
    #pragma unroll 8
    for (int dd = 0; dd < 64; ++dd) {
        float xa = __shfl(xv.x, dd);
        float xb = __shfl(xv.y, dd);
        a0 += xa * Wr[(2 * dd) * OUT_DIM + o0]     + xb * Wr[(2 * dd + 1) * OUT_DIM + o0];
        a1 += xa * Wr[(2 * dd) * OUT_DIM + o0 + 1] + xb * Wr[(2 * dd + 1) * OUT_DIM + o0 + 1];
    }
    atomicAdd(out + (long)d * OUT_DIM + o0, a0);
    atomicAdd(out + (long)d * OUT_DIM + o0 + 1, a1);
}

__global__ __launch_bounds__(256) void relu_k(float* __restrict__ out, long n4)
{
    long i = (long)blockIdx.x * blockDim.x + threadIdx.x;
    if (i >= n4) return;
    float4 v = ((float4*)out)[i];
    v.x = fmaxf(v.x, 0.f); v.y = fmaxf(v.y, 0.f);
    v.z = fmaxf(v.z, 0.f); v.w = fmaxf(v.w, 0.f);
    ((float4*)out)[i] = v;
}

static inline size_t align256(size_t x) { return (x + 255) & ~(size_t)255; }

extern "C" void kernel_launch(void* const* d_in, const int* in_sizes, int n_in,
                              void* d_out, int out_size, void* d_ws, size_t ws_size,
                              hipStream_t stream)
{
    const float* x      = (const float*)d_in[0];
    const float* weight = (const float*)d_in[1];
    const float* slw    = (const float*)d_in[2];
    const float* bias   = (const float*)d_in[3];
    const int*   ei     = (const int*)d_in[4];
    const int*   et     = (const int*)d_in[5];

    const int N = in_sizes[0] / IN_DIM;
    const int E = in_sizes[5];
    const int* src  = ei;
    const int* dstp = ei + E;

    float* out = (float*)d_out;

    const int n8 = N * 8;   // CSR bins keyed (dst<<3)|rel

    // workspace layout (cursor..part contiguous -> one k_zero covers both)
    size_t off = 0;
    const size_t xb_off   = off; off += align256((size_t)N * 128 * 2);
    const size_t wb_off   = off; off += align256((size_t)128 * 1152 * 2);
    const size_t rp_off   = off; off += align256((size_t)(n8 + 1) * 4);
    const size_t cur_off  = off; off += align256((size_t)n8 * 4);
    const size_t pt_off   = off; off += align256(256 * 8);
    const size_t pk_off   = off; off += align256((size_t)E * 4);
    const size_t need_bf16 = off;

    const int nchunks = (n8 + 4095) >> 12;   // 4096 elems per scan block

    if (ws_size >= need_bf16 && N <= (1 << 17) && nchunks <= 256) {
        char* base   = (char*)d_ws;
        u16* xb      = (u16*)(base + xb_off);
        u16* WbT     = (u16*)(base + wb_off);
        int* row_ptr = (int*)(base + rp_off);
        int* cursor  = (int*)(base + cur_off);
        unsigned long long* part = (unsigned long long*)(base + pt_off);
        int* packed  = (int*)(base + pk_off);

        // zero cursor + lookback state (custom kernel, not fillBuffer)
        const int n4z = (int)((pk_off - cur_off) / 16);
        k_zero<<<dim3((n4z + 255) / 256), 256, 0, stream>>>(
            (int4*)(base + cur_off), n4z);

        const int BA = (int)(((long)N * 128 / 4 + 255) / 256);
        const int BB = (128 * 1152 / 4 + 255) / 256;   // 144
        const int BD = (E + 255) / 256;
        k_prep<<<dim3(BA + BB + BD), 256, 0, stream>>>(
            x, weight, slw, dstp, et, xb, WbT, cursor, row_ptr, N, E, n8, BA, BB);

        k_scan_lb<<<dim3(nchunks), 512, 0, stream>>>(cursor, row_ptr, cursor, part, n8);
        k_fill<<<dim3((E + 255) / 256), 256, 0, stream>>>(src, dstp, et, cursor, packed, E);

        const int ntiles = (N + NPB - 1) / NPB;
        fused_rgcn<<<dim3(ntiles), 512, 0, stream>>>(
            xb, WbT, bias, row_ptr, packed, out, N);
    } else if (ws_size >= (size_t)NUM_RELS * N * 128 * 4) {
        gemm128<<<dim3(512, 1, 1), 256, 0, stream>>>(x, slw, bias, out, N);
        long nt = (long)E * 64;
        edge_direct<<<dim3((nt + 255) / 256), 256, 0, stream>>>(x, weight, src, dstp, et, out, E);
        long n4 = (long)N * OUT_DIM / 4;
        relu_k<<<dim3((n4 + 255) / 256), 256, 0, stream>>>(out, n4);
    } else {
        gemm128<<<dim3(512, 1, 1), 256, 0, stream>>>(x, slw, bias, out, N);
        long nt = (long)E * 64;
        edge_direct<<<dim3((nt + 255) / 256), 256, 0, stream>>>(x, weight, src, dstp, et, out, E);
        long n4 = (long)N * OUT_DIM / 4;
        relu_k<<<dim3((n4 + 255) / 256), 256, 0, stream>>>(out, n4);
    }
}